// Round 1
// baseline (187.282 us; speedup 1.0000x reference)
//
#include <hip/hip_runtime.h>
#include <hip/hip_bf16.h>

#define BATCH 4096
#define DIM 4096
#define NSPLIT 64
#define ROWS_PB 128
#define BN_EPS 1e-3f

typedef __attribute__((ext_vector_type(8))) short bf16x8;
typedef __attribute__((ext_vector_type(4))) float f32x4;

__device__ inline unsigned short f2bf(float f) {
    union { float f; unsigned int u; } c; c.f = f;
    unsigned int u = c.u;
    u += 0x7FFFu + ((u >> 16) & 1u);   // round-to-nearest-even
    return (unsigned short)(u >> 16);
}

// Pass 1: per (split, 128-row chunk): out = X_chunk @ W_s + b  (bf16 MFMA),
// store bf16 intermediate to ws, accumulate per-column sum & sumsq.
__global__ __launch_bounds__(256) void gemm_stats(
    const float* __restrict__ x, const float* __restrict__ w,
    const float* __restrict__ bias,
    unsigned short* __restrict__ wsout,
    float* __restrict__ gsum, float* __restrict__ gsumsq)
{
    // +8 pad: ds_read_b128 row stride 144B -> only 2-way bank aliasing (free)
    __shared__ unsigned short xs[ROWS_PB][72];
    __shared__ unsigned short wt[64][72];   // W^T of this split's 64x64 block
    __shared__ float bcol[64];
    __shared__ float csum[64], csumsq[64];

    const int s  = blockIdx.y;
    const int r0 = blockIdx.x * ROWS_PB;
    const int t  = threadIdx.x;

    if (t < 64) { bcol[t] = bias[s*64 + t]; csum[t] = 0.f; csumsq[t] = 0.f; }

    // stage X chunk (128x64 fp32 -> bf16), coalesced float4 loads
    for (int i = t; i < ROWS_PB * 16; i += 256) {
        int row = i >> 4, c4 = i & 15;
        float4 v = *(const float4*)(x + (size_t)(r0 + row) * DIM + s*64 + c4*4);
        ushort4 u;
        u.x = f2bf(v.x); u.y = f2bf(v.y); u.z = f2bf(v.z); u.w = f2bf(v.w);
        *(ushort4*)&xs[row][c4 * 4] = u;
    }
    // stage W_s transposed (coalesced global read, scattered LDS write - one-time)
    for (int i = t; i < 64 * 64; i += 256) {
        int k = i >> 6, n = i & 63;
        wt[n][k] = f2bf(w[(size_t)(s*64 + k) * DIM + s*64 + n]);
    }
    __syncthreads();

    const int lane = t & 63;
    const int wave = t >> 6;
    const int quad = lane >> 4;
    const int l16  = lane & 15;
    const int wrow = wave * 32;          // each wave: 32 rows x 64 cols

    // accumulators pre-seeded with bias (C/D: col = l16-based, bias is per-col)
    f32x4 acc[2][4];
    for (int rt = 0; rt < 2; rt++)
        for (int ct = 0; ct < 4; ct++) {
            float b = bcol[ct*16 + l16];
            acc[rt][ct] = (f32x4){b, b, b, b};
        }

    // A frag: A[m=l16][k=quad*8+j]; B frag: B[k=quad*8+j][n=l16] (from W^T rows)
    bf16x8 afrag[2][2], bfrag[4][2];
    for (int rt = 0; rt < 2; rt++)
        for (int kk = 0; kk < 2; kk++)
            afrag[rt][kk] = *(const bf16x8*)&xs[wrow + rt*16 + l16][kk*32 + quad*8];
    for (int ct = 0; ct < 4; ct++)
        for (int kk = 0; kk < 2; kk++)
            bfrag[ct][kk] = *(const bf16x8*)&wt[ct*16 + l16][kk*32 + quad*8];

    for (int kk = 0; kk < 2; kk++)
        for (int rt = 0; rt < 2; rt++)
            for (int ct = 0; ct < 4; ct++)
                acc[rt][ct] = __builtin_amdgcn_mfma_f32_16x16x32_bf16(
                    afrag[rt][kk], bfrag[ct][kk], acc[rt][ct], 0, 0, 0);

    // epilogue: store bf16 intermediate + per-column sum/sumsq
    float s1[4], s2[4];
    for (int ct = 0; ct < 4; ct++) { s1[ct] = 0.f; s2[ct] = 0.f; }
    for (int rt = 0; rt < 2; rt++)
        for (int ct = 0; ct < 4; ct++) {
            int col = ct*16 + l16;
            for (int r = 0; r < 4; r++) {
                float v = acc[rt][ct][r];                    // row = quad*4+r
                int row = r0 + wrow + rt*16 + quad*4 + r;
                wsout[(size_t)row * DIM + s*64 + col] = f2bf(v);
                s1[ct] += v; s2[ct] += v * v;
            }
        }
    for (int ct = 0; ct < 4; ct++) {
        float a = s1[ct], b = s2[ct];
        a += __shfl_xor(a, 16); b += __shfl_xor(b, 16);
        a += __shfl_xor(a, 32); b += __shfl_xor(b, 32);
        if (quad == 0) {
            atomicAdd(&csum[ct*16 + l16], a);
            atomicAdd(&csumsq[ct*16 + l16], b);
        }
    }
    __syncthreads();
    if (t < 64) {
        atomicAdd(&gsum[s*64 + t], csum[t]);
        atomicAdd(&gsumsq[s*64 + t], csumsq[t]);
    }
}

// Pass 2a: fold BN stats + gamma/beta into per-column scale/shift
__global__ __launch_bounds__(256) void finalize_stats(
    const float* __restrict__ gsum, const float* __restrict__ gsumsq,
    const float* __restrict__ gamma, const float* __restrict__ beta,
    float* __restrict__ scale, float* __restrict__ shiftv)
{
    int j = blockIdx.x * 256 + threadIdx.x;
    float mean = gsum[j] * (1.f / BATCH);
    float var  = gsumsq[j] * (1.f / BATCH) - mean * mean;
    float rstd = rsqrtf(var + BN_EPS);
    float sc = gamma[j] * rstd;
    scale[j]  = sc;
    shiftv[j] = beta[j] - mean * sc;
}

// Pass 2b: elementwise normalize + relu, bf16 -> fp32
__global__ __launch_bounds__(256) void normalize(
    const unsigned short* __restrict__ wsout,
    const float* __restrict__ scale, const float* __restrict__ shiftv,
    float* __restrict__ out)
{
    size_t i = ((size_t)blockIdx.x * 256 + threadIdx.x) * 8;
    int col = (int)(i & (DIM - 1));
    uint4 u = *(const uint4*)(wsout + i);
    float4 sc0 = *(const float4*)(scale + col);
    float4 sc1 = *(const float4*)(scale + col + 4);
    float4 sh0 = *(const float4*)(shiftv + col);
    float4 sh1 = *(const float4*)(shiftv + col + 4);
    float v0 = __uint_as_float(u.x << 16), v1 = __uint_as_float(u.x & 0xFFFF0000u);
    float v2 = __uint_as_float(u.y << 16), v3 = __uint_as_float(u.y & 0xFFFF0000u);
    float v4 = __uint_as_float(u.z << 16), v5 = __uint_as_float(u.z & 0xFFFF0000u);
    float v6 = __uint_as_float(u.w << 16), v7 = __uint_as_float(u.w & 0xFFFF0000u);
    float4 o0, o1;
    o0.x = fmaxf(fmaf(v0, sc0.x, sh0.x), 0.f);
    o0.y = fmaxf(fmaf(v1, sc0.y, sh0.y), 0.f);
    o0.z = fmaxf(fmaf(v2, sc0.z, sh0.z), 0.f);
    o0.w = fmaxf(fmaf(v3, sc0.w, sh0.w), 0.f);
    o1.x = fmaxf(fmaf(v4, sc1.x, sh1.x), 0.f);
    o1.y = fmaxf(fmaf(v5, sc1.y, sh1.y), 0.f);
    o1.z = fmaxf(fmaf(v6, sc1.z, sh1.z), 0.f);
    o1.w = fmaxf(fmaf(v7, sc1.w, sh1.w), 0.f);
    *(float4*)(out + i)     = o0;
    *(float4*)(out + i + 4) = o1;
}

extern "C" void kernel_launch(void* const* d_in, const int* in_sizes, int n_in,
                              void* d_out, int out_size, void* d_ws, size_t ws_size,
                              hipStream_t stream) {
    const float* x     = (const float*)d_in[0];
    const float* w     = (const float*)d_in[1];
    const float* bias  = (const float*)d_in[2];
    const float* gamma = (const float*)d_in[3];
    const float* beta  = (const float*)d_in[4];
    float* out = (float*)d_out;

    unsigned short* wsout = (unsigned short*)d_ws;            // 32 MB bf16 intermediate
    float* gsum   = (float*)((char*)d_ws + (size_t)BATCH * DIM * 2);
    float* gsumsq = gsum + DIM;
    float* scale  = gsum + 2 * DIM;
    float* shiftv = gsum + 3 * DIM;

    hipMemsetAsync(gsum, 0, 2 * DIM * sizeof(float), stream); // zero sum/sumsq (ws is poisoned)

    gemm_stats<<<dim3(BATCH / ROWS_PB, NSPLIT), 256, 0, stream>>>(
        x, w, bias, wsout, gsum, gsumsq);
    finalize_stats<<<DIM / 256, 256, 0, stream>>>(gsum, gsumsq, gamma, beta, scale, shiftv);
    normalize<<<(size_t)BATCH * DIM / 8 / 256, 256, 0, stream>>>(wsout, scale, shiftv, out);
}